// Round 9
// baseline (56.246 us; speedup 1.0000x reference)
//
#include <hip/hip_runtime.h>

#define EPS 1e-8f

__device__ __forceinline__ float sigmoidf_(float x) {
    return 1.0f / (1.0f + expf(-x));
}

// ---------------------------------------------------------------------------
// Three-kernel chunked scan, scalar lanes, maximal thread parallelism.
//   sub-chunk length Ls=25, Cs=T/25 sub-chunks per chain.
//   k1  : thread (bf,j) zero-carry scans sub-chunk j -> S[j][bf] (j<Cs-1).
//   mid : thread bf sequentially turns S into carry-in prefixes P[j][bf].
//   emit: thread (bf,j) loads its exact carry-in P[j][bf], rescans sub-chunk
//         (mag L3-warm), normalizes, stores. 2570 blocks -> full occupancy.
// Load batches of BT with a compiler memory barrier force MLP.
// ---------------------------------------------------------------------------

template <int LS, int BT>
__global__ __launch_bounds__(256)
void fns9_aggregate(const float* __restrict__ mag,
                    const float* __restrict__ alpha,
                    float* __restrict__ S,   // [Cs-1][BF]
                    int B, int T, int F, int Cs1) {
    static_assert(LS % BT == 0, "");
    const int BF = B * F;
    int g = blockIdx.x * blockDim.x + threadIdx.x;
    if (g >= BF * Cs1) return;
    const int bf = g % BF;
    const int j  = g / BF;
    const int b  = bf / F;
    const int f  = bf - b * F;

    const float a   = sigmoidf_(alpha[f]);
    const float oma = 1.0f - a;

    const float* p = mag + ((size_t)b * T + (size_t)j * LS) * F + f;

    float local = 0.0f;
#pragma unroll
    for (int blk = 0; blk < LS / BT; ++blk) {
        float m[BT];
#pragma unroll
        for (int i = 0; i < BT; ++i)              // BT independent loads
            m[i] = p[(size_t)(blk * BT + i) * F];
        asm volatile("" ::: "memory");            // keep loads clustered
#pragma unroll
        for (int i = 0; i < BT; ++i)              // serial recurrence
            local = local * oma + (m[i] * m[i]) * a;
    }
    S[(size_t)j * BF + bf] = local;
}

template <int LS>
__global__ __launch_bounds__(256)
void fns9_prefix(const float* __restrict__ s0,
                 const float* __restrict__ alpha,
                 const float* __restrict__ S,   // [Cs-1][BF]
                 float* __restrict__ P,         // [Cs][BF] carry-ins
                 int B, int F, int Cs) {
    const int BF = B * F;
    int bf = blockIdx.x * blockDim.x + threadIdx.x;
    if (bf >= BF) return;
    const int b = bf / F;
    const int f = bf - b * F;

    const float a   = sigmoidf_(alpha[f]);
    const float oma = 1.0f - a;
    float D = 1.0f;                               // (1-a)^LS via product
#pragma unroll
    for (int i = 0; i < LS; ++i) D *= oma;

    float carry = s0[bf];                         // exact sequential pass
    for (int j = 0; j < Cs; ++j) {
        P[(size_t)j * BF + bf] = carry;
        if (j < Cs - 1)
            carry = carry * D + S[(size_t)j * BF + bf];
    }
}

template <int LS, int BT>
__global__ __launch_bounds__(256)
void fns9_emit(const float* __restrict__ mag,
               const float* __restrict__ weights,
               const float* __restrict__ bias,
               const float* __restrict__ alpha,
               const float* __restrict__ P,   // [Cs][BF]
               float* __restrict__ out,
               int B, int T, int F, int Cs) {
    static_assert(LS % BT == 0, "");
    const int BF = B * F;
    int g = blockIdx.x * blockDim.x + threadIdx.x;
    if (g >= BF * Cs) return;
    const int bf = g % BF;
    const int j  = g / BF;
    const int b  = bf / F;
    const int f  = bf - b * F;

    const float a   = sigmoidf_(alpha[f]);
    const float oma = 1.0f - a;
    const float w   = weights[f];
    const float bi  = bias[f];

    float carry = P[(size_t)j * BF + bf];         // exact carry-in, 1 load

    const float* p = mag + ((size_t)b * T + (size_t)j * LS) * F + f;
    float*       o = out + ((size_t)b * T + (size_t)j * LS) * F + f;

#pragma unroll
    for (int blk = 0; blk < LS / BT; ++blk) {
        float m[BT];
#pragma unroll
        for (int i = 0; i < BT; ++i)              // BT independent loads
            m[i] = p[(size_t)(blk * BT + i) * F];
        asm volatile("" ::: "memory");            // keep loads clustered
        float r[BT];
#pragma unroll
        for (int i = 0; i < BT; ++i) {            // serial recurrence + norm
            carry = carry * oma + (m[i] * m[i]) * a;
            r[i] = m[i] * __builtin_amdgcn_rcpf(sqrtf(carry) + EPS) * w + bi;
        }
#pragma unroll
        for (int i = 0; i < BT; ++i)
            o[(size_t)(blk * BT + i) * F] = r[i];
    }
}

// ---------------------------------------------------------------------------
// Proven R4 2-kernel path (fallback for odd shapes / small ws).
// ---------------------------------------------------------------------------
template <int L>
__global__ __launch_bounds__(256)
void fns4_aggregate(const float* __restrict__ mag,
                    const float* __restrict__ alpha,
                    float* __restrict__ S,
                    int B, int T, int F, int C) {
    const int BF = B * F;
    int g = blockIdx.x * blockDim.x + threadIdx.x;
    if (g >= BF * C) return;
    const int bf = g % BF;
    const int c  = g / BF;
    const int b  = bf / F;
    const int f  = bf - b * F;

    const float a   = sigmoidf_(alpha[f]);
    const float oma = 1.0f - a;
    const float* p = mag + ((size_t)b * T + (size_t)c * L) * F + f;

    float local = 0.0f;
#pragma unroll
    for (int t = 0; t < L; ++t) {
        float m = p[(size_t)t * F];
        local = local * oma + (m * m) * a;
    }
    S[(size_t)c * BF + bf] = local;
}

template <int L>
__global__ __launch_bounds__(256)
void fns4_emit(const float* __restrict__ mag,
               const float* __restrict__ s0,
               const float* __restrict__ weights,
               const float* __restrict__ bias,
               const float* __restrict__ alpha,
               const float* __restrict__ S,
               float* __restrict__ out,
               int B, int T, int F, int C) {
    const int BF = B * F;
    int g = blockIdx.x * blockDim.x + threadIdx.x;
    if (g >= BF * C) return;
    const int bf = g % BF;
    const int c  = g / BF;
    const int b  = bf / F;
    const int f  = bf - b * F;

    const float a   = sigmoidf_(alpha[f]);
    const float oma = 1.0f - a;
    const float w   = weights[f];
    const float bi  = bias[f];

    float carry = s0[bf];
    if (c > 0) {
        float D = 1.0f;
#pragma unroll
        for (int i = 0; i < L; ++i) D *= oma;
        for (int j = 0; j < c; ++j)
            carry = carry * D + S[(size_t)j * BF + bf];
    }

    const float* p = mag + ((size_t)b * T + (size_t)c * L) * F + f;
    float*       o = out + ((size_t)b * T + (size_t)c * L) * F + f;

#pragma unroll
    for (int t = 0; t < L; ++t) {
        float m = p[(size_t)t * F];
        carry = carry * oma + (m * m) * a;
        o[(size_t)t * F] = m / (sqrtf(carry) + EPS) * w + bi;
    }
}

__global__ void fns_fallback(const float* __restrict__ mag,
                             const float* __restrict__ s0,
                             const float* __restrict__ weights,
                             const float* __restrict__ bias,
                             const float* __restrict__ alpha,
                             float* __restrict__ out,
                             int B, int T, int F) {
    int bf = blockIdx.x * blockDim.x + threadIdx.x;
    int BF = B * F;
    if (bf >= BF) return;
    int b = bf / F;
    int f = bf - b * F;

    float a  = sigmoidf_(alpha[f]);
    float w  = weights[f];
    float bi = bias[f];

    float carry = s0[bf];
    const float* p = mag + (size_t)b * T * F + f;
    float*       o = out + (size_t)b * T * F + f;

    for (int t = 0; t < T; ++t) {
        float m = p[(size_t)t * F];
        carry = carry * (1.0f - a) + (m * m) * a;
        o[(size_t)t * F] = m / (sqrtf(carry) + EPS) * w + bi;
    }
}

extern "C" void kernel_launch(void* const* d_in, const int* in_sizes, int n_in,
                              void* d_out, int out_size, void* d_ws, size_t ws_size,
                              hipStream_t stream) {
    const float* mag     = (const float*)d_in[0];
    const float* s0      = (const float*)d_in[1];
    const float* weights = (const float*)d_in[2];
    const float* bias    = (const float*)d_in[3];
    const float* alpha   = (const float*)d_in[4];
    float* out = (float*)d_out;

    int F  = in_sizes[4];          // alpha is [1, F]
    int BF = in_sizes[1];          // s is [B, F]
    int B  = BF / F;
    int T  = in_sizes[0] / BF;     // mag is [B, T, F]

    constexpr int LS = 25;         // sub-chunk length
    constexpr int BT = 5;          // loads in flight per batch
    if (T % LS == 0) {
        int Cs  = T / LS;          // 40 for T=1000
        int Cs1 = Cs - 1;
        size_t sBytes = (size_t)Cs1 * BF * sizeof(float);
        size_t pOff   = (sBytes + 255) & ~(size_t)255;
        size_t need   = pOff + (size_t)Cs * BF * sizeof(float);
        if (Cs1 >= 1 && ws_size >= need) {
            float* S = (float*)d_ws;
            float* P = (float*)((char*)d_ws + pOff);

            int n1 = BF * Cs1;                     // 641,472 -> 2506 blocks
            int n3 = BF * Cs;                      // 657,920 -> 2570 blocks
            fns9_aggregate<LS, BT><<<(n1 + 255) / 256, 256, 0, stream>>>(
                mag, alpha, S, B, T, F, Cs1);
            fns9_prefix<LS><<<(BF + 255) / 256, 256, 0, stream>>>(
                s0, alpha, S, P, B, F, Cs);
            fns9_emit<LS, BT><<<(n3 + 255) / 256, 256, 0, stream>>>(
                mag, weights, bias, alpha, P, out, B, T, F, Cs);
            return;
        }
    }

    // fallback: proven R4 2-kernel path (L=50)
    constexpr int L = 50;
    if (T % L == 0) {
        int C = T / L;
        size_t need = (size_t)C * BF * sizeof(float);
        if (ws_size >= need) {
            float* S = (float*)d_ws;
            int n = BF * C;
            fns4_aggregate<L><<<(n + 255) / 256, 256, 0, stream>>>(
                mag, alpha, S, B, T, F, C);
            fns4_emit<L><<<(n + 255) / 256, 256, 0, stream>>>(
                mag, s0, weights, bias, alpha, S, out, B, T, F, C);
            return;
        }
    }

    int threads = 256;
    int blocks  = (BF + threads - 1) / threads;
    fns_fallback<<<blocks, threads, 0, stream>>>(mag, s0, weights, bias,
                                                 alpha, out, B, T, F);
}

// Round 10
// 43.136 us; speedup vs baseline: 1.3039x; 1.3039x over previous
//
#include <hip/hip_runtime.h>

#define EPS 1e-8f

__device__ __forceinline__ float sigmoidf_(float x) {
    return 1.0f / (1.0f + expf(-x));
}

// ---------------------------------------------------------------------------
// Two-kernel chunked scan (R4 structure) + forced deep load prefetch in emit.
// Chains (b,f) as bf in [0,BF); time in C chunks of L=50.
// Thread (bf,c) owns chunk c of chain bf; consecutive threads = consecutive
// bf -> wave-coalesced 256 B per load instruction.
//
// k1  : zero-carry local scan -> chunk aggregate S[c][bf] (chunks 0..C-2).
// emit: Horner-reconstruct exact carry-in from s0 + S[0..c) (arithmetic
//       identical to a sequential middle pass), then PREFETCH ALL L elements
//       into registers (asm memory clobber pins loads before the store loop,
//       forcing ~L loads in flight per wave), then scan+normalize+store.
// ---------------------------------------------------------------------------

template <int L>
__global__ __launch_bounds__(256)
void fns10_aggregate(const float* __restrict__ mag,
                     const float* __restrict__ alpha,
                     float* __restrict__ S,   // [C-1][BF]
                     int B, int T, int F, int C1) {
    const int BF = B * F;
    int g = blockIdx.x * blockDim.x + threadIdx.x;
    if (g >= BF * C1) return;
    const int bf = g % BF;
    const int c  = g / BF;
    const int b  = bf / F;
    const int f  = bf - b * F;

    const float a   = sigmoidf_(alpha[f]);
    const float oma = 1.0f - a;

    const float* p = mag + ((size_t)b * T + (size_t)c * L) * F + f;

    float local = 0.0f;
#pragma unroll
    for (int t = 0; t < L; ++t) {
        float m = p[(size_t)t * F];
        local = local * oma + (m * m) * a;   // exact reference recurrence form
    }
    S[(size_t)c * BF + bf] = local;
}

template <int L>
__global__ __launch_bounds__(256)
void fns10_emit(const float* __restrict__ mag,
                const float* __restrict__ s0,
                const float* __restrict__ weights,
                const float* __restrict__ bias,
                const float* __restrict__ alpha,
                const float* __restrict__ S,   // [C-1][BF]
                float* __restrict__ out,
                int B, int T, int F, int C) {
    const int BF = B * F;
    int g = blockIdx.x * blockDim.x + threadIdx.x;
    if (g >= BF * C) return;
    const int bf = g % BF;
    const int c  = g / BF;
    const int b  = bf / F;
    const int f  = bf - b * F;

    const float a   = sigmoidf_(alpha[f]);
    const float oma = 1.0f - a;
    const float w   = weights[f];
    const float bi  = bias[f];

    // exact carry-in for chunk c (Horner over preceding chunk aggregates;
    // identical arithmetic to a sequential middle pass)
    float carry = s0[bf];
    if (c > 0) {
        float D = 1.0f;                      // (1-a)^L via product
#pragma unroll
        for (int i = 0; i < L; ++i) D *= oma;
        for (int j = 0; j < c; ++j)
            carry = carry * D + S[(size_t)j * BF + bf];
    }

    const float* p = mag + ((size_t)b * T + (size_t)c * L) * F + f;
    float*       o = out + ((size_t)b * T + (size_t)c * L) * F + f;

    // ---- deep prefetch: all L loads issued before any store ----
    float m[L];
#pragma unroll
    for (int t = 0; t < L; ++t)
        m[t] = p[(size_t)t * F];
    // Memory clobber: no store may be hoisted above, no load sunk below.
    // Forces all L load destinations live -> ~L loads in flight per wave.
    asm volatile("" ::: "memory");

#pragma unroll
    for (int t = 0; t < L; ++t) {
        carry = carry * oma + (m[t] * m[t]) * a;
        // 1/(sqrt+eps) via hw rcp (~1 ulp); bounded output -> abs err ~1e-6
        o[(size_t)t * F] = m[t] * __builtin_amdgcn_rcpf(sqrtf(carry) + EPS) * w + bi;
    }
}

// ---------------------------------------------------------------------------
// Fallback: one thread per (b,f) chain (general shapes / tiny workspace).
// ---------------------------------------------------------------------------
__global__ void fns_fallback(const float* __restrict__ mag,
                             const float* __restrict__ s0,
                             const float* __restrict__ weights,
                             const float* __restrict__ bias,
                             const float* __restrict__ alpha,
                             float* __restrict__ out,
                             int B, int T, int F) {
    int bf = blockIdx.x * blockDim.x + threadIdx.x;
    int BF = B * F;
    if (bf >= BF) return;
    int b = bf / F;
    int f = bf - b * F;

    float a  = sigmoidf_(alpha[f]);
    float w  = weights[f];
    float bi = bias[f];

    float carry = s0[bf];
    const float* p = mag + (size_t)b * T * F + f;
    float*       o = out + (size_t)b * T * F + f;

    for (int t = 0; t < T; ++t) {
        float m = p[(size_t)t * F];
        carry = carry * (1.0f - a) + (m * m) * a;
        o[(size_t)t * F] = m / (sqrtf(carry) + EPS) * w + bi;
    }
}

extern "C" void kernel_launch(void* const* d_in, const int* in_sizes, int n_in,
                              void* d_out, int out_size, void* d_ws, size_t ws_size,
                              hipStream_t stream) {
    const float* mag     = (const float*)d_in[0];
    const float* s0      = (const float*)d_in[1];
    const float* weights = (const float*)d_in[2];
    const float* bias    = (const float*)d_in[3];
    const float* alpha   = (const float*)d_in[4];
    float* out = (float*)d_out;

    int F  = in_sizes[4];          // alpha is [1, F]
    int BF = in_sizes[1];          // s is [B, F]
    int B  = BF / F;
    int T  = in_sizes[0] / BF;     // mag is [B, T, F]

    constexpr int L = 50;          // chunk length (compile-time, full unroll)
    if (T % L == 0) {
        int C  = T / L;            // 20 for T=1000
        int C1 = C - 1;
        size_t need = (size_t)C1 * BF * sizeof(float);
        if (C1 >= 1 && ws_size >= need) {
            float* S = (float*)d_ws;
            int n1 = BF * C1;                    // 312,512
            int n2 = BF * C;                     // 328,960
            fns10_aggregate<L><<<(n1 + 255) / 256, 256, 0, stream>>>(
                mag, alpha, S, B, T, F, C1);
            fns10_emit<L><<<(n2 + 255) / 256, 256, 0, stream>>>(
                mag, s0, weights, bias, alpha, S, out, B, T, F, C);
            return;
        }
    }

    int threads = 256;
    int blocks  = (BF + threads - 1) / threads;
    fns_fallback<<<blocks, threads, 0, stream>>>(mag, s0, weights, bias,
                                                 alpha, out, B, T, F);
}